// Round 9
// baseline (20222.325 us; speedup 1.0000x reference)
//
#include <hip/hip_runtime.h>

#define DIM   64
#define HID   256
#define TLEN  21
#define BS    65536
#define BLOCK 512
#define WAVES 8
#define ROWS_PER_WAVE 32
#define ROWS_PER_BLOCK 256
#define NBLOCKS (BS / ROWS_PER_BLOCK)   // 256
#define PROBE_STEPS 120                  // 6x the real step count

typedef __bf16    bf16x8   __attribute__((ext_vector_type(8)));
typedef float     f32x16   __attribute__((ext_vector_type(16)));
typedef float     f32x4    __attribute__((ext_vector_type(4)));
typedef float     f32x2    __attribute__((ext_vector_type(2)));
typedef unsigned  uint32x4 __attribute__((ext_vector_type(4)));

__device__ __forceinline__ bf16x8 as_bf16x8(uint32x4 u) {
    return __builtin_bit_cast(bf16x8, u);
}

__device__ __forceinline__ unsigned pack2(float a, float b) {
    __bf16 x = (__bf16)a, y = (__bf16)b;
    unsigned short ux = __builtin_bit_cast(unsigned short, x);
    unsigned short uy = __builtin_bit_cast(unsigned short, y);
    return (unsigned)ux | ((unsigned)uy << 16);
}

__device__ __forceinline__ float tanh_f(float x) {
    float e = __expf(2.0f * x);
    return 1.0f - __fdividef(2.0f, e + 1.0f);
}

__device__ __forceinline__ uint32x4 pack_lo(f32x16 v) {
    uint32x4 r;
    r[0] = pack2(v[0], v[1]); r[1] = pack2(v[2], v[3]);
    r[2] = pack2(v[4], v[5]); r[3] = pack2(v[6], v[7]);
    return r;
}
__device__ __forceinline__ uint32x4 pack_hi(f32x16 v) {
    uint32x4 r;
    r[0] = pack2(v[8], v[9]);   r[1] = pack2(v[10], v[11]);
    r[2] = pack2(v[12], v[13]); r[3] = pack2(v[14], v[15]);
    return r;
}
__device__ __forceinline__ f32x16 axpy16(float c, f32x16 k, f32x16 z) {
    f32x16 r;
    #pragma unroll
    for (int i = 0; i < 16; i++) r[i] = fmaf(c, k[i], z[i]);
    return r;
}

struct KOut { f32x16 a, b; };

// Fragment conventions: verified (absmax 0.031). See round 2-6 comments.
__device__ __forceinline__ KOut feval(const uint32x4* A1, const uint32x4* A2,
                                      const f32x4* b1q, const f32x4* b2q,
                                      int lane, int g,
                                      uint32x4 bk0, uint32x4 bk1,
                                      uint32x4 bk2, uint32x4 bk3)
{
    f32x16 d2a, d2b;
    #pragma unroll
    for (int q = 0; q < 4; q++) {
        f32x4 ba = b2q[(0 + g) * 4 + q];
        f32x4 bb = b2q[(2 + g) * 4 + q];
        #pragma unroll
        for (int i = 0; i < 4; i++) { d2a[q * 4 + i] = ba[i]; d2b[q * 4 + i] = bb[i]; }
    }

    #pragma unroll
    for (int ht = 0; ht < 8; ht++) {
        f32x16 d1;
        #pragma unroll
        for (int q = 0; q < 4; q++) {
            f32x4 bq = b1q[(ht * 2 + g) * 4 + q];
            #pragma unroll
            for (int i = 0; i < 4; i++) d1[q * 4 + i] = bq[i];
        }
        d1 = __builtin_amdgcn_mfma_f32_32x32x16_bf16(
                 as_bf16x8(A1[(ht * 4 + 0) * 64 + lane]), as_bf16x8(bk0), d1, 0, 0, 0);
        d1 = __builtin_amdgcn_mfma_f32_32x32x16_bf16(
                 as_bf16x8(A1[(ht * 4 + 1) * 64 + lane]), as_bf16x8(bk1), d1, 0, 0, 0);
        d1 = __builtin_amdgcn_mfma_f32_32x32x16_bf16(
                 as_bf16x8(A1[(ht * 4 + 2) * 64 + lane]), as_bf16x8(bk2), d1, 0, 0, 0);
        d1 = __builtin_amdgcn_mfma_f32_32x32x16_bf16(
                 as_bf16x8(A1[(ht * 4 + 3) * 64 + lane]), as_bf16x8(bk3), d1, 0, 0, 0);

        uint32x4 lo, hi;
        lo[0] = pack2(tanh_f(d1[0]),  tanh_f(d1[1]));
        lo[1] = pack2(tanh_f(d1[2]),  tanh_f(d1[3]));
        lo[2] = pack2(tanh_f(d1[4]),  tanh_f(d1[5]));
        lo[3] = pack2(tanh_f(d1[6]),  tanh_f(d1[7]));
        hi[0] = pack2(tanh_f(d1[8]),  tanh_f(d1[9]));
        hi[1] = pack2(tanh_f(d1[10]), tanh_f(d1[11]));
        hi[2] = pack2(tanh_f(d1[12]), tanh_f(d1[13]));
        hi[3] = pack2(tanh_f(d1[14]), tanh_f(d1[15]));

        d2a = __builtin_amdgcn_mfma_f32_32x32x16_bf16(
                  as_bf16x8(A2[(2 * ht) * 64 + lane]), as_bf16x8(lo), d2a, 0, 0, 0);
        d2b = __builtin_amdgcn_mfma_f32_32x32x16_bf16(
                  as_bf16x8(A2[(16 + 2 * ht) * 64 + lane]), as_bf16x8(lo), d2b, 0, 0, 0);
        d2a = __builtin_amdgcn_mfma_f32_32x32x16_bf16(
                  as_bf16x8(A2[(2 * ht + 1) * 64 + lane]), as_bf16x8(hi), d2a, 0, 0, 0);
        d2b = __builtin_amdgcn_mfma_f32_32x32x16_bf16(
                  as_bf16x8(A2[(16 + 2 * ht + 1) * 64 + lane]), as_bf16x8(hi), d2b, 0, 0, 0);
    }

    return KOut{d2a, d2b};
}

// Shared prologue: stage weights/biases into LDS (identical in both kernels).
__device__ __forceinline__ void stage_weights(
    const float* W1, const float* b1, const float* W2, const float* b2,
    unsigned short* sA1, unsigned short* sA2, float* sb1, float* sb2, int tid)
{
    for (int idx = tid; idx < DIM * HID; idx += BLOCK) {
        int hid = idx & (HID - 1);
        int dim = idx >> 8;
        int c   = hid & 31, ht = hid >> 5;
        int j   = (dim & 3) | (((dim >> 3) & 1) << 2);
        int gg  = (dim >> 2) & 1;
        int kt  = dim >> 4;
        __bf16 bv = (__bf16)W1[idx];
        sA1[((ht * 4 + kt) * 64 + gg * 32 + c) * 8 + j] =
            __builtin_bit_cast(unsigned short, bv);
    }
    for (int idx = tid; idx < HID * DIM; idx += BLOCK) {
        int dim = idx & 63;
        int hid = idx >> 6;
        int c   = dim & 31, mt = dim >> 5;
        int hlo = hid & 15;
        int j   = (hlo & 3) | (((hlo >> 3) & 1) << 2);
        int gg  = (hlo >> 2) & 1;
        int kt2 = hid >> 4;
        __bf16 bv = (__bf16)W2[idx];
        sA2[((mt * 16 + kt2) * 64 + gg * 32 + c) * 8 + j] =
            __builtin_bit_cast(unsigned short, bv);
    }
    if (tid < 256) {
        int r = tid & 15, gg = (tid >> 4) & 1, ht = tid >> 5;
        sb1[tid] = b1[ht * 32 + (r & 3) + 8 * (r >> 2) + 4 * gg];
    }
    if (tid < 64) {
        int r = tid & 15, gg = (tid >> 4) & 1, mt = tid >> 5;
        sb2[tid] = b2[mt * 32 + (r & 3) + 8 * (r >> 2) + 4 * gg];
    }
}

// ===========================================================================
// DIAGNOSTIC PROBE (round 9): identical feval/RK4 chain, PROBE_STEPS=120
// (6x), NO trajectory stores. Final state kept live via asm sink. Writes
// nothing. If the invariant ~7.3 GB/20-step excess FETCH comes from the
// feval chain (H1), this shows ~44 GB; if from the store path (H2), ~0.
// ===========================================================================
extern "C" __global__ __launch_bounds__(BLOCK, 2) void probe_rk4_nostore(
    const float* __restrict__ z0, const float* __restrict__ tarr,
    const float* __restrict__ W1, const float* __restrict__ b1,
    const float* __restrict__ W2, const float* __restrict__ b2)
{
    __shared__ __align__(16) unsigned short sA1[32 * 64 * 8];
    __shared__ __align__(16) unsigned short sA2[32 * 64 * 8];
    __shared__ __align__(16) float sb1[8 * 2 * 16];
    __shared__ __align__(16) float sb2[2 * 2 * 16];
    __shared__ __align__(16) float trbuf[WAVES][2048];

    const int tid  = threadIdx.x;
    const int lane = tid & 63;
    const int wv   = tid >> 6;
    const int g    = lane >> 5;
    const int ln31 = lane & 31;

    stage_weights(W1, b1, W2, b2, sA1, sA2, sb1, sb2, tid);
    __syncthreads();

    const int rowbase = blockIdx.x * ROWS_PER_BLOCK + wv * ROWS_PER_WAVE;
    float* tb = trbuf[wv];

    const uint32x4* A1  = reinterpret_cast<const uint32x4*>(sA1);
    const uint32x4* A2  = reinterpret_cast<const uint32x4*>(sA2);
    const f32x4*    b1q = reinterpret_cast<const f32x4*>(sb1);
    const f32x4*    b2q = reinterpret_cast<const f32x4*>(sb2);

    #pragma unroll
    for (int p = 0; p < 8; p++) {
        int batch  = (lane >> 4) + 4 * p;
        int linear = lane * 16 + p * 1024;
        f32x4 v = *reinterpret_cast<const f32x4*>(
            z0 + (size_t)(rowbase + batch) * DIM + (lane & 15) * 4);
        *reinterpret_cast<f32x4*>((char*)tb + (linear ^ ((batch & 7) << 4))) = v;
    }

    f32x16 za, zb;
    #pragma unroll
    for (int rp = 0; rp < 8; rp++) {
        int d    = (rp & 1) * 2 + 8 * (rp >> 1) + 4 * g;
        int byte = ln31 * 256 + d * 4;
        f32x2 v = *reinterpret_cast<f32x2*>((char*)tb + (byte ^ ((ln31 & 7) << 4)));
        za[2 * rp] = v[0]; za[2 * rp + 1] = v[1];
    }
    #pragma unroll
    for (int rp = 0; rp < 8; rp++) {
        int d    = 32 + (rp & 1) * 2 + 8 * (rp >> 1) + 4 * g;
        int byte = ln31 * 256 + d * 4;
        f32x2 v = *reinterpret_cast<f32x2*>((char*)tb + (byte ^ ((ln31 & 7) << 4)));
        zb[2 * rp] = v[0]; zb[2 * rp + 1] = v[1];
    }

    const float h  = tarr[1] - tarr[0];
    const float h2 = 0.5f * h;
    const float h3 = h * (1.0f / 3.0f);
    const float h6 = h * (1.0f / 6.0f);

    #pragma unroll 1
    for (int s = 0; s < PROBE_STEPS; s++) {
        KOut k1 = feval(A1, A2, b1q, b2q, lane, g,
                        pack_lo(za), pack_hi(za), pack_lo(zb), pack_hi(zb));
        f32x16 zfa = axpy16(h6, k1.a, za), zfb = axpy16(h6, k1.b, zb);
        f32x16 pa  = axpy16(h2, k1.a, za), pb  = axpy16(h2, k1.b, zb);

        KOut k2 = feval(A1, A2, b1q, b2q, lane, g,
                        pack_lo(pa), pack_hi(pa), pack_lo(pb), pack_hi(pb));
        zfa = axpy16(h3, k2.a, zfa); zfb = axpy16(h3, k2.b, zfb);
        pa  = axpy16(h2, k2.a, za);  pb  = axpy16(h2, k2.b, zb);

        KOut k3 = feval(A1, A2, b1q, b2q, lane, g,
                        pack_lo(pa), pack_hi(pa), pack_lo(pb), pack_hi(pb));
        zfa = axpy16(h3, k3.a, zfa); zfb = axpy16(h3, k3.b, zfb);
        pa  = axpy16(h, k3.a, za);   pb  = axpy16(h, k3.b, zb);

        KOut k4 = feval(A1, A2, b1q, b2q, lane, g,
                        pack_lo(pa), pack_hi(pa), pack_lo(pb), pack_hi(pb));
        za = axpy16(h6, k4.a, zfa);  zb = axpy16(h6, k4.b, zfb);
    }

    float sk = 0.0f;
    #pragma unroll
    for (int i = 0; i < 16; i++) sk += za[i] + zb[i];
    asm volatile("" :: "v"(sk));   // keep the whole chain live; no memory
}

// ===========================================================================
// REAL KERNEL — exact round-6 structure (best verified: 2.45 ms, absmax 0.031)
// ===========================================================================
extern "C" __global__ __launch_bounds__(BLOCK, 2) void node_mfma_kernel(
    const float* __restrict__ z0, const float* __restrict__ tarr,
    const float* __restrict__ W1, const float* __restrict__ b1,
    const float* __restrict__ W2, const float* __restrict__ b2,
    float* __restrict__ out)
{
    __shared__ __align__(16) unsigned short sA1[32 * 64 * 8];
    __shared__ __align__(16) unsigned short sA2[32 * 64 * 8];
    __shared__ __align__(16) float sb1[8 * 2 * 16];
    __shared__ __align__(16) float sb2[2 * 2 * 16];
    __shared__ __align__(16) float trbuf[WAVES][2048];

    const int tid  = threadIdx.x;
    const int lane = tid & 63;
    const int wv   = tid >> 6;
    const int g    = lane >> 5;
    const int ln31 = lane & 31;

    stage_weights(W1, b1, W2, b2, sA1, sA2, sb1, sb2, tid);

    {
        const f32x4* src = reinterpret_cast<const f32x4*>(z0 + (size_t)blockIdx.x * ROWS_PER_BLOCK * DIM);
        f32x4*       dst = reinterpret_cast<f32x4*>(out + (size_t)blockIdx.x * ROWS_PER_BLOCK * DIM);
        for (int i = tid; i < ROWS_PER_BLOCK * DIM / 4; i += BLOCK) dst[i] = src[i];
    }

    __syncthreads();

    const int rowbase = blockIdx.x * ROWS_PER_BLOCK + wv * ROWS_PER_WAVE;
    float* tb = trbuf[wv];

    const uint32x4* A1  = reinterpret_cast<const uint32x4*>(sA1);
    const uint32x4* A2  = reinterpret_cast<const uint32x4*>(sA2);
    const f32x4*    b1q = reinterpret_cast<const f32x4*>(sb1);
    const f32x4*    b2q = reinterpret_cast<const f32x4*>(sb2);

    #pragma unroll
    for (int p = 0; p < 8; p++) {
        int batch  = (lane >> 4) + 4 * p;
        int linear = lane * 16 + p * 1024;
        f32x4 v = *reinterpret_cast<const f32x4*>(
            z0 + (size_t)(rowbase + batch) * DIM + (lane & 15) * 4);
        *reinterpret_cast<f32x4*>((char*)tb + (linear ^ ((batch & 7) << 4))) = v;
    }

    f32x16 za, zb;
    #pragma unroll
    for (int rp = 0; rp < 8; rp++) {
        int d    = (rp & 1) * 2 + 8 * (rp >> 1) + 4 * g;
        int byte = ln31 * 256 + d * 4;
        f32x2 v = *reinterpret_cast<f32x2*>((char*)tb + (byte ^ ((ln31 & 7) << 4)));
        za[2 * rp] = v[0]; za[2 * rp + 1] = v[1];
    }
    #pragma unroll
    for (int rp = 0; rp < 8; rp++) {
        int d    = 32 + (rp & 1) * 2 + 8 * (rp >> 1) + 4 * g;
        int byte = ln31 * 256 + d * 4;
        f32x2 v = *reinterpret_cast<f32x2*>((char*)tb + (byte ^ ((ln31 & 7) << 4)));
        zb[2 * rp] = v[0]; zb[2 * rp + 1] = v[1];
    }

    #pragma unroll 1
    for (int s = 0; s < TLEN - 1; s++) {
        const float h  = tarr[s + 1] - tarr[s];
        const float h2 = 0.5f * h;
        const float h3 = h * (1.0f / 3.0f);
        const float h6 = h * (1.0f / 6.0f);

        KOut k1 = feval(A1, A2, b1q, b2q, lane, g,
                        pack_lo(za), pack_hi(za), pack_lo(zb), pack_hi(zb));
        f32x16 zfa = axpy16(h6, k1.a, za), zfb = axpy16(h6, k1.b, zb);
        f32x16 pa  = axpy16(h2, k1.a, za), pb  = axpy16(h2, k1.b, zb);

        KOut k2 = feval(A1, A2, b1q, b2q, lane, g,
                        pack_lo(pa), pack_hi(pa), pack_lo(pb), pack_hi(pb));
        zfa = axpy16(h3, k2.a, zfa); zfb = axpy16(h3, k2.b, zfb);
        pa  = axpy16(h2, k2.a, za);  pb  = axpy16(h2, k2.b, zb);

        KOut k3 = feval(A1, A2, b1q, b2q, lane, g,
                        pack_lo(pa), pack_hi(pa), pack_lo(pb), pack_hi(pb));
        zfa = axpy16(h3, k3.a, zfa); zfb = axpy16(h3, k3.b, zfb);
        pa  = axpy16(h, k3.a, za);   pb  = axpy16(h, k3.b, zb);

        KOut k4 = feval(A1, A2, b1q, b2q, lane, g,
                        pack_lo(pa), pack_hi(pa), pack_lo(pb), pack_hi(pb));
        za = axpy16(h6, k4.a, zfa);  zb = axpy16(h6, k4.b, zfb);

        #pragma unroll
        for (int rp = 0; rp < 8; rp++) {
            int d    = (rp & 1) * 2 + 8 * (rp >> 1) + 4 * g;
            int byte = ln31 * 256 + d * 4;
            f32x2 v; v[0] = za[2 * rp]; v[1] = za[2 * rp + 1];
            *reinterpret_cast<f32x2*>((char*)tb + (byte ^ ((ln31 & 7) << 4))) = v;
        }
        #pragma unroll
        for (int rp = 0; rp < 8; rp++) {
            int d    = 32 + (rp & 1) * 2 + 8 * (rp >> 1) + 4 * g;
            int byte = ln31 * 256 + d * 4;
            f32x2 v; v[0] = zb[2 * rp]; v[1] = zb[2 * rp + 1];
            *reinterpret_cast<f32x2*>((char*)tb + (byte ^ ((ln31 & 7) << 4))) = v;
        }
        float* obase = out + ((size_t)(s + 1) * BS + rowbase) * DIM;
        #pragma unroll
        for (int p = 0; p < 8; p++) {
            int batch  = (lane >> 4) + 4 * p;
            int linear = lane * 16 + p * 1024;
            f32x4 v = *reinterpret_cast<f32x4*>((char*)tb + (linear ^ ((batch & 7) << 4)));
            *reinterpret_cast<f32x4*>(obase + batch * DIM + (lane & 15) * 4) = v;
        }
    }
}

extern "C" void kernel_launch(void* const* d_in, const int* in_sizes, int n_in,
                              void* d_out, int out_size, void* d_ws, size_t ws_size,
                              hipStream_t stream) {
    const float* z0 = (const float*)d_in[0];
    const float* t  = (const float*)d_in[1];
    const float* W1 = (const float*)d_in[2];
    const float* b1 = (const float*)d_in[3];
    const float* W2 = (const float*)d_in[4];
    const float* b2 = (const float*)d_in[5];
    float* out = (float*)d_out;

    // Diagnostic probe first (writes nothing), real kernel second.
    probe_rk4_nostore<<<dim3(NBLOCKS), dim3(BLOCK), 0, stream>>>(
        z0, t, W1, b1, W2, b2);
    node_mfma_kernel<<<dim3(NBLOCKS), dim3(BLOCK), 0, stream>>>(
        z0, t, W1, b1, W2, b2, out);
}

// Round 10
// 3088.706 us; speedup vs baseline: 6.5472x; 6.5472x over previous
//
#include <hip/hip_runtime.h>

#define DIM   64
#define HID   256
#define TLEN  21
#define BS    65536
#define BLOCK 512
#define WAVES 8
#define ROWS_PER_WAVE 16
#define ROWS_PER_BLOCK 128              // 8 waves * 16 rows
#define NBLOCKS (BS / ROWS_PER_BLOCK)   // 512

typedef __bf16    bf16x8   __attribute__((ext_vector_type(8)));
typedef float     f32x16   __attribute__((ext_vector_type(16)));
typedef float     f32x4    __attribute__((ext_vector_type(4)));
typedef float     f32x2    __attribute__((ext_vector_type(2)));
typedef unsigned  uint32x4 __attribute__((ext_vector_type(4)));

__device__ __forceinline__ bf16x8 as_bf16x8(uint32x4 u) {
    return __builtin_bit_cast(bf16x8, u);
}

__device__ __forceinline__ unsigned pack2(float a, float b) {
    __bf16 x = (__bf16)a, y = (__bf16)b;
    unsigned short ux = __builtin_bit_cast(unsigned short, x);
    unsigned short uy = __builtin_bit_cast(unsigned short, y);
    return (unsigned)ux | ((unsigned)uy << 16);
}

// tanh(x) = 1 - 2/(e^{2x}+1). Saturates correctly through exp overflow.
__device__ __forceinline__ float tanh_f(float x) {
    float e = __expf(2.0f * x);
    return 1.0f - __fdividef(2.0f, e + 1.0f);
}

__device__ __forceinline__ uint32x4 pack_lo(f32x16 v) {
    uint32x4 r;
    r[0] = pack2(v[0], v[1]); r[1] = pack2(v[2], v[3]);
    r[2] = pack2(v[4], v[5]); r[3] = pack2(v[6], v[7]);
    return r;
}
__device__ __forceinline__ uint32x4 pack_hi(f32x16 v) {
    uint32x4 r;
    r[0] = pack2(v[8], v[9]);   r[1] = pack2(v[10], v[11]);
    r[2] = pack2(v[12], v[13]); r[3] = pack2(v[14], v[15]);
    return r;
}
__device__ __forceinline__ uint32x4 packaxpy_lo(float c, f32x16 k, f32x16 z) {
    uint32x4 r;
    r[0] = pack2(fmaf(c, k[0], z[0]), fmaf(c, k[1], z[1]));
    r[1] = pack2(fmaf(c, k[2], z[2]), fmaf(c, k[3], z[3]));
    r[2] = pack2(fmaf(c, k[4], z[4]), fmaf(c, k[5], z[5]));
    r[3] = pack2(fmaf(c, k[6], z[6]), fmaf(c, k[7], z[7]));
    return r;
}
__device__ __forceinline__ uint32x4 packaxpy_hi(float c, f32x16 k, f32x16 z) {
    uint32x4 r;
    r[0] = pack2(fmaf(c, k[8],  z[8]),  fmaf(c, k[9],  z[9]));
    r[1] = pack2(fmaf(c, k[10], z[10]), fmaf(c, k[11], z[11]));
    r[2] = pack2(fmaf(c, k[12], z[12]), fmaf(c, k[13], z[13]));
    r[3] = pack2(fmaf(c, k[14], z[14]), fmaf(c, k[15], z[15]));
    return r;
}
__device__ __forceinline__ f32x16 axpy16(float c, f32x16 k, f32x16 z) {
    f32x16 r;
    #pragma unroll
    for (int i = 0; i < 16; i++) r[i] = fmaf(c, k[i], z[i]);
    return r;
}

// ---------------------------------------------------------------------------
// Round-10: MFMA shape 16x16x32 (was 32x32x16). R9's ablation proved the
// invariant ~370 MB/step HBM FETCH is generated inside the feval chain =
// scratch spill-reload under a 128-arch-VGPR allocation that no attribute
// moves (launch_bounds x2, waves_per_eu all null, VGPR_Count==128 six
// rounds). Fix by construction: 16x16 tiles -> wave covers 16 batch rows,
// per-lane state halves (z 16, zf 16, C/D = f32x4), peak arch liveness
// ~85 < 128. Same FLOPs, no redundancy, no cross-wave exchange.
//
// Fragment conventions (mfma_f32_16x16x32_bf16, swapped chain):
//   matmul1: D1[hid][b] = A1(W1T)*B1(zT)    16 ht-tiles x 2 k-tiles (K=dim)
//   matmul2: D2[dim][b] = A2(W2T)*B2(tanhT)  4 mt-tiles x 8 k-tiles (K=hid)
// C/D (m89-verified): col = lane&15, row = 4*(lane>>4) + reg.
// A/B k-slot map: we choose logical k = P(q,j) = 4q + (j&3) + 16*(j>>2)
// (q = lane>>4). Applied identically to A (weights pre-permuted in LDS) and
// B (packed from C/D-ordered registers) it self-cancels for any identical
// HW A/B k-layout. Frag words become sequential pack2s of C/D regs, and
// biases stage in NATURAL order (C/D row = 4q+r).
// ---------------------------------------------------------------------------

__device__ __forceinline__ f32x16 feval(const uint32x4* A1, const uint32x4* A2,
                                        const float* sb1, const float* sb2,
                                        int lane, int q,
                                        uint32x4 bkA, uint32x4 bkB)
{
    bf16x8 b0 = as_bf16x8(bkA);
    bf16x8 b1v = as_bf16x8(bkB);

    f32x4 d20 = *reinterpret_cast<const f32x4*>(sb2 +  0 + q * 4);
    f32x4 d21 = *reinterpret_cast<const f32x4*>(sb2 + 16 + q * 4);
    f32x4 d22 = *reinterpret_cast<const f32x4*>(sb2 + 32 + q * 4);
    f32x4 d23 = *reinterpret_cast<const f32x4*>(sb2 + 48 + q * 4);

    #pragma unroll
    for (int kt2 = 0; kt2 < 8; kt2++) {
        f32x4 d1e = *reinterpret_cast<const f32x4*>(sb1 + (2 * kt2) * 16 + q * 4);
        f32x4 d1o = *reinterpret_cast<const f32x4*>(sb1 + (2 * kt2 + 1) * 16 + q * 4);

        d1e = __builtin_amdgcn_mfma_f32_16x16x32_bf16(
                  as_bf16x8(A1[(4 * kt2 + 0) * 64 + lane]), b0,  d1e, 0, 0, 0);
        d1e = __builtin_amdgcn_mfma_f32_16x16x32_bf16(
                  as_bf16x8(A1[(4 * kt2 + 1) * 64 + lane]), b1v, d1e, 0, 0, 0);
        d1o = __builtin_amdgcn_mfma_f32_16x16x32_bf16(
                  as_bf16x8(A1[(4 * kt2 + 2) * 64 + lane]), b0,  d1o, 0, 0, 0);
        d1o = __builtin_amdgcn_mfma_f32_16x16x32_bf16(
                  as_bf16x8(A1[(4 * kt2 + 3) * 64 + lane]), b1v, d1o, 0, 0, 0);

        uint32x4 bt;
        bt[0] = pack2(tanh_f(d1e[0]), tanh_f(d1e[1]));
        bt[1] = pack2(tanh_f(d1e[2]), tanh_f(d1e[3]));
        bt[2] = pack2(tanh_f(d1o[0]), tanh_f(d1o[1]));
        bt[3] = pack2(tanh_f(d1o[2]), tanh_f(d1o[3]));
        bf16x8 btb = as_bf16x8(bt);

        d20 = __builtin_amdgcn_mfma_f32_16x16x32_bf16(
                  as_bf16x8(A2[(0 * 8 + kt2) * 64 + lane]), btb, d20, 0, 0, 0);
        d21 = __builtin_amdgcn_mfma_f32_16x16x32_bf16(
                  as_bf16x8(A2[(1 * 8 + kt2) * 64 + lane]), btb, d21, 0, 0, 0);
        d22 = __builtin_amdgcn_mfma_f32_16x16x32_bf16(
                  as_bf16x8(A2[(2 * 8 + kt2) * 64 + lane]), btb, d22, 0, 0, 0);
        d23 = __builtin_amdgcn_mfma_f32_16x16x32_bf16(
                  as_bf16x8(A2[(3 * 8 + kt2) * 64 + lane]), btb, d23, 0, 0, 0);
    }

    f32x16 k;
    #pragma unroll
    for (int i = 0; i < 4; i++) {
        k[i]      = d20[i];
        k[4 + i]  = d21[i];
        k[8 + i]  = d22[i];
        k[12 + i] = d23[i];
    }
    return k;
}

extern "C" __global__ __launch_bounds__(BLOCK, 2) void node_mfma_kernel(
    const float* __restrict__ z0, const float* __restrict__ tarr,
    const float* __restrict__ W1, const float* __restrict__ b1,
    const float* __restrict__ W2, const float* __restrict__ b2,
    float* __restrict__ out)
{
    __shared__ __align__(16) unsigned short sA1[32 * 64 * 8];  // 32 KiB [(ht*2+kt)][lane][j]
    __shared__ __align__(16) unsigned short sA2[32 * 64 * 8];  // 32 KiB [(mt*8+kt2)][lane][j]
    __shared__ __align__(16) float sb1[HID];                   // natural order
    __shared__ __align__(16) float sb2[DIM];                   // natural order
    __shared__ __align__(16) float trbuf[WAVES][1024];         // 4 KiB per wave

    const int tid  = threadIdx.x;
    const int lane = tid & 63;
    const int wv   = tid >> 6;
    const int q    = lane >> 4;
    const int bcol = lane & 15;

    // ---- stage W1 fragments: coalesced reads, P-permuted LDS writes ----
    for (int idx = tid; idx < DIM * HID; idx += BLOCK) {
        int hid = idx & (HID - 1);
        int dim = idx >> 8;
        int ht = hid >> 4, row = hid & 15;
        int kt = dim >> 5, dlo = dim & 31;
        int j  = (dlo & 3) | ((dlo >> 4) << 2);
        int qq = (dlo >> 2) & 3;
        __bf16 bv = (__bf16)W1[idx];
        sA1[((ht * 2 + kt) * 64 + qq * 16 + row) * 8 + j] =
            __builtin_bit_cast(unsigned short, bv);
    }
    // ---- stage W2 fragments ----
    for (int idx = tid; idx < HID * DIM; idx += BLOCK) {
        int dim = idx & (DIM - 1);
        int hid = idx >> 6;
        int mt  = dim >> 4, row = dim & 15;
        int kt2 = hid >> 5, hlo = hid & 31;
        int j   = (hlo & 3) | ((hlo >> 4) << 2);
        int qq  = (hlo >> 2) & 3;
        __bf16 bv = (__bf16)W2[idx];
        sA2[((mt * 8 + kt2) * 64 + qq * 16 + row) * 8 + j] =
            __builtin_bit_cast(unsigned short, bv);
    }
    // ---- biases: natural order (C/D row = 4q + r) ----
    if (tid < HID) sb1[tid] = b1[tid];
    if (tid < DIM) sb2[tid] = b2[tid];

    // ---- out[0] = z0 (coalesced block-slice copy) ----
    {
        const f32x4* src = reinterpret_cast<const f32x4*>(z0 + (size_t)blockIdx.x * ROWS_PER_BLOCK * DIM);
        f32x4*       dst = reinterpret_cast<f32x4*>(out + (size_t)blockIdx.x * ROWS_PER_BLOCK * DIM);
        for (int i = tid; i < ROWS_PER_BLOCK * DIM / 4; i += BLOCK) dst[i] = src[i];
    }

    __syncthreads();

    const int rowbase = blockIdx.x * ROWS_PER_BLOCK + wv * ROWS_PER_WAVE;
    float* tb = trbuf[wv];

    const uint32x4* A1 = reinterpret_cast<const uint32x4*>(sA1);
    const uint32x4* A2 = reinterpret_cast<const uint32x4*>(sA2);

    // ---- z0 -> registers via per-wave LDS transpose (XOR-swizzled) ----
    #pragma unroll
    for (int p = 0; p < 4; p++) {
        int batch  = q + 4 * p;                     // 0..15
        int linear = batch * 256 + bcol * 16;       // [batch][dim] bytes
        f32x4 v = *reinterpret_cast<const f32x4*>(
            z0 + (size_t)(rowbase + batch) * DIM + bcol * 4);
        *reinterpret_cast<f32x4*>((char*)tb + (linear ^ ((batch & 7) << 4))) = v;
    }

    f32x16 za;   // za[mt*4 + r] = z[dim = mt*16 + 4q + r] of batch column bcol
    #pragma unroll
    for (int mt = 0; mt < 4; mt++)
        #pragma unroll
        for (int rp = 0; rp < 2; rp++) {
            int dim  = mt * 16 + 4 * q + 2 * rp;
            int byte = bcol * 256 + dim * 4;
            f32x2 v = *reinterpret_cast<f32x2*>((char*)tb + (byte ^ ((bcol & 7) << 4)));
            za[mt * 4 + 2 * rp]     = v[0];
            za[mt * 4 + 2 * rp + 1] = v[1];
        }

    #pragma unroll 1
    for (int s = 0; s < TLEN - 1; s++) {
        const float h  = tarr[s + 1] - tarr[s];
        const float h2 = 0.5f * h;
        const float h3 = h * (1.0f / 3.0f);
        const float h6 = h * (1.0f / 6.0f);

        f32x16 k1 = feval(A1, A2, sb1, sb2, lane, q, pack_lo(za), pack_hi(za));
        f32x16 zf = axpy16(h6, k1, za);

        f32x16 k2 = feval(A1, A2, sb1, sb2, lane, q,
                          packaxpy_lo(h2, k1, za), packaxpy_hi(h2, k1, za));
        zf = axpy16(h3, k2, zf);

        f32x16 k3 = feval(A1, A2, sb1, sb2, lane, q,
                          packaxpy_lo(h2, k2, za), packaxpy_hi(h2, k2, za));
        zf = axpy16(h3, k3, zf);

        f32x16 k4 = feval(A1, A2, sb1, sb2, lane, q,
                          packaxpy_lo(h, k3, za), packaxpy_hi(h, k3, za));
        za = axpy16(h6, k4, zf);

        // ---- store trajectory[s+1] via per-wave LDS transpose ----
        #pragma unroll
        for (int mt = 0; mt < 4; mt++)
            #pragma unroll
            for (int rp = 0; rp < 2; rp++) {
                int dim  = mt * 16 + 4 * q + 2 * rp;
                int byte = bcol * 256 + dim * 4;
                f32x2 v; v[0] = za[mt * 4 + 2 * rp]; v[1] = za[mt * 4 + 2 * rp + 1];
                *reinterpret_cast<f32x2*>((char*)tb + (byte ^ ((bcol & 7) << 4))) = v;
            }
        float* obase = out + ((size_t)(s + 1) * BS + rowbase) * DIM;
        #pragma unroll
        for (int p = 0; p < 4; p++) {
            int batch  = q + 4 * p;
            int linear = batch * 256 + bcol * 16;
            f32x4 v = *reinterpret_cast<f32x4*>((char*)tb + (linear ^ ((batch & 7) << 4)));
            *reinterpret_cast<f32x4*>(obase + batch * DIM + bcol * 4) = v;
        }
    }
}

extern "C" void kernel_launch(void* const* d_in, const int* in_sizes, int n_in,
                              void* d_out, int out_size, void* d_ws, size_t ws_size,
                              hipStream_t stream) {
    const float* z0 = (const float*)d_in[0];
    const float* t  = (const float*)d_in[1];
    const float* W1 = (const float*)d_in[2];
    const float* b1 = (const float*)d_in[3];
    const float* W2 = (const float*)d_in[4];
    const float* b2 = (const float*)d_in[5];
    float* out = (float*)d_out;

    node_mfma_kernel<<<dim3(NBLOCKS), dim3(BLOCK), 0, stream>>>(
        z0, t, W1, b1, W2, b2, out);
}

// Round 11
// 2827.211 us; speedup vs baseline: 7.1527x; 1.0925x over previous
//
#include <hip/hip_runtime.h>

#define DIM   64
#define HID   256
#define TLEN  21
#define BS    65536
#define BLOCK 512
#define WAVES 8
#define ROWS_PER_WAVE 16
#define ROWS_PER_BLOCK 128              // 8 waves * 16 rows
#define NBLOCKS (BS / ROWS_PER_BLOCK)   // 512

typedef __bf16    bf16x8   __attribute__((ext_vector_type(8)));
typedef float     f32x16   __attribute__((ext_vector_type(16)));
typedef float     f32x4    __attribute__((ext_vector_type(4)));
typedef unsigned  uint32x4 __attribute__((ext_vector_type(4)));

__device__ __forceinline__ bf16x8 as_bf16x8(uint32x4 u) {
    return __builtin_bit_cast(bf16x8, u);
}

__device__ __forceinline__ unsigned pack2(float a, float b) {
    __bf16 x = (__bf16)a, y = (__bf16)b;
    unsigned short ux = __builtin_bit_cast(unsigned short, x);
    unsigned short uy = __builtin_bit_cast(unsigned short, y);
    return (unsigned)ux | ((unsigned)uy << 16);
}

// tanh(x) = 1 - 2/(e^{2x}+1). Saturates correctly through exp overflow.
__device__ __forceinline__ float tanh_f(float x) {
    float e = __expf(2.0f * x);
    return 1.0f - __fdividef(2.0f, e + 1.0f);
}

// ---------------------------------------------------------------------------
// Round-11: ALL persistent state (za, zf) lives in LDS, column layout
// state[i*64 + lane] (bank = lane mod 32 -> 2-way alias = free). R10's
// counters showed the state vectors are memory-homed ALWAYS (excess FETCH ~=
// one reload per source-level read, invariant to liveness restructuring and
// register-budget attributes across 6 rounds; R1 without MFMA had none).
// So: never keep ANY wide value live across a feval. Each k is consumed
// (zf update + next probe pack) immediately after its feval; za re-read from
// LDS each time. Cross-feval arch state ~= 10 regs. za-in-LDS doubles as the
// trajectory-store transpose source (scalar gather, 2-way banks, coalesced
// dwordx4 global stores).
//
// feval = byte-identical to R10 (verified, absmax 0.03125):
//   mfma_f32_16x16x32_bf16, swapped chain; C/D col=lane&15, row=4*(lane>>4)+reg
//   k-slot map P(q,j) = 4q + (j&3) + 16*(j>>2) on both A (LDS-prepermuted)
//   and B (packed from C/D-ordered regs) -> self-cancels; biases natural order.
// ---------------------------------------------------------------------------

__device__ __forceinline__ f32x16 feval(const uint32x4* A1, const uint32x4* A2,
                                        const float* sb1, const float* sb2,
                                        int lane, int q,
                                        uint32x4 bkA, uint32x4 bkB)
{
    bf16x8 b0  = as_bf16x8(bkA);
    bf16x8 b1v = as_bf16x8(bkB);

    f32x4 d20 = *reinterpret_cast<const f32x4*>(sb2 +  0 + q * 4);
    f32x4 d21 = *reinterpret_cast<const f32x4*>(sb2 + 16 + q * 4);
    f32x4 d22 = *reinterpret_cast<const f32x4*>(sb2 + 32 + q * 4);
    f32x4 d23 = *reinterpret_cast<const f32x4*>(sb2 + 48 + q * 4);

    #pragma unroll
    for (int kt2 = 0; kt2 < 8; kt2++) {
        f32x4 d1e = *reinterpret_cast<const f32x4*>(sb1 + (2 * kt2) * 16 + q * 4);
        f32x4 d1o = *reinterpret_cast<const f32x4*>(sb1 + (2 * kt2 + 1) * 16 + q * 4);

        d1e = __builtin_amdgcn_mfma_f32_16x16x32_bf16(
                  as_bf16x8(A1[(4 * kt2 + 0) * 64 + lane]), b0,  d1e, 0, 0, 0);
        d1e = __builtin_amdgcn_mfma_f32_16x16x32_bf16(
                  as_bf16x8(A1[(4 * kt2 + 1) * 64 + lane]), b1v, d1e, 0, 0, 0);
        d1o = __builtin_amdgcn_mfma_f32_16x16x32_bf16(
                  as_bf16x8(A1[(4 * kt2 + 2) * 64 + lane]), b0,  d1o, 0, 0, 0);
        d1o = __builtin_amdgcn_mfma_f32_16x16x32_bf16(
                  as_bf16x8(A1[(4 * kt2 + 3) * 64 + lane]), b1v, d1o, 0, 0, 0);

        uint32x4 bt;
        bt[0] = pack2(tanh_f(d1e[0]), tanh_f(d1e[1]));
        bt[1] = pack2(tanh_f(d1e[2]), tanh_f(d1e[3]));
        bt[2] = pack2(tanh_f(d1o[0]), tanh_f(d1o[1]));
        bt[3] = pack2(tanh_f(d1o[2]), tanh_f(d1o[3]));
        bf16x8 btb = as_bf16x8(bt);

        d20 = __builtin_amdgcn_mfma_f32_16x16x32_bf16(
                  as_bf16x8(A2[(0 * 8 + kt2) * 64 + lane]), btb, d20, 0, 0, 0);
        d21 = __builtin_amdgcn_mfma_f32_16x16x32_bf16(
                  as_bf16x8(A2[(1 * 8 + kt2) * 64 + lane]), btb, d21, 0, 0, 0);
        d22 = __builtin_amdgcn_mfma_f32_16x16x32_bf16(
                  as_bf16x8(A2[(2 * 8 + kt2) * 64 + lane]), btb, d22, 0, 0, 0);
        d23 = __builtin_amdgcn_mfma_f32_16x16x32_bf16(
                  as_bf16x8(A2[(3 * 8 + kt2) * 64 + lane]), btb, d23, 0, 0, 0);
    }

    f32x16 k;
    #pragma unroll
    for (int i = 0; i < 4; i++) {
        k[i]      = d20[i];
        k[4 + i]  = d21[i];
        k[8 + i]  = d22[i];
        k[12 + i] = d23[i];
    }
    return k;
}

extern "C" __global__ __launch_bounds__(BLOCK, 1) void node_mfma_kernel(
    const float* __restrict__ z0, const float* __restrict__ tarr,
    const float* __restrict__ W1, const float* __restrict__ b1,
    const float* __restrict__ W2, const float* __restrict__ b2,
    float* __restrict__ out)
{
    __shared__ __align__(16) unsigned short sA1[32 * 64 * 8];   // 32 KiB
    __shared__ __align__(16) unsigned short sA2[32 * 64 * 8];   // 32 KiB
    __shared__ __align__(16) float sb1[HID];                    // natural order
    __shared__ __align__(16) float sb2[DIM];
    __shared__ __align__(16) float state[WAVES][2][16 * 64];    // za, zf: 64 KiB

    const int tid  = threadIdx.x;
    const int lane = tid & 63;
    const int wv   = tid >> 6;
    const int q    = lane >> 4;
    const int bcol = lane & 15;

    // ---- stage W1 fragments: coalesced reads, P-permuted LDS writes ----
    for (int idx = tid; idx < DIM * HID; idx += BLOCK) {
        int hid = idx & (HID - 1);
        int dim = idx >> 8;
        int ht = hid >> 4, row = hid & 15;
        int kt = dim >> 5, dlo = dim & 31;
        int j  = (dlo & 3) | ((dlo >> 4) << 2);
        int qq = (dlo >> 2) & 3;
        __bf16 bv = (__bf16)W1[idx];
        sA1[((ht * 2 + kt) * 64 + qq * 16 + row) * 8 + j] =
            __builtin_bit_cast(unsigned short, bv);
    }
    // ---- stage W2 fragments ----
    for (int idx = tid; idx < HID * DIM; idx += BLOCK) {
        int dim = idx & (DIM - 1);
        int hid = idx >> 6;
        int mt  = dim >> 4, row = dim & 15;
        int kt2 = hid >> 5, hlo = hid & 31;
        int j   = (hlo & 3) | ((hlo >> 4) << 2);
        int qq  = (hlo >> 2) & 3;
        __bf16 bv = (__bf16)W2[idx];
        sA2[((mt * 8 + kt2) * 64 + qq * 16 + row) * 8 + j] =
            __builtin_bit_cast(unsigned short, bv);
    }
    if (tid < HID) sb1[tid] = b1[tid];
    if (tid < DIM) sb2[tid] = b2[tid];

    // ---- out[0] = z0 (coalesced block-slice copy) ----
    {
        const f32x4* src = reinterpret_cast<const f32x4*>(z0 + (size_t)blockIdx.x * ROWS_PER_BLOCK * DIM);
        f32x4*       dst = reinterpret_cast<f32x4*>(out + (size_t)blockIdx.x * ROWS_PER_BLOCK * DIM);
        for (int i = tid; i < ROWS_PER_BLOCK * DIM / 4; i += BLOCK) dst[i] = src[i];
    }

    __syncthreads();

    const int rowbase = blockIdx.x * ROWS_PER_BLOCK + wv * ROWS_PER_WAVE;
    float* za_l = state[wv][0];   // za_l[i*64 + lane]: z[batch=bcol][dim=16*(i>>2)+4q+(i&3)]
    float* zf_l = state[wv][1];

    const uint32x4* A1 = reinterpret_cast<const uint32x4*>(sA1);
    const uint32x4* A2 = reinterpret_cast<const uint32x4*>(sA2);

    // ---- z0 -> za_l: coalesced dwordx4 loads, scalar LDS scatter (2-way) ----
    #pragma unroll
    for (int p = 0; p < 4; p++) {
        int d0    = (lane >> 4) + 4 * p;     // f32x4 chunk index 0..15
        int batch = lane & 15;
        f32x4 v = *reinterpret_cast<const f32x4*>(
            z0 + (size_t)(rowbase + batch) * DIM + d0 * 4);
        #pragma unroll
        for (int c = 0; c < 4; c++)
            za_l[(((d0 >> 2) * 4 + c) * 64) + (d0 & 3) * 16 + batch] = v[c];
    }

    #pragma unroll 1
    for (int s = 0; s < TLEN - 1; s++) {
        const float h  = tarr[s + 1] - tarr[s];
        const float h2 = 0.5f * h;
        const float h3 = h * (1.0f / 3.0f);
        const float h6 = h * (1.0f / 6.0f);

        // ---- k1: pack from za (LDS) ----
        uint32x4 bkA, bkB;
        #pragma unroll
        for (int w = 0; w < 4; w++)
            bkA[w] = pack2(za_l[(2 * w) * 64 + lane], za_l[(2 * w + 1) * 64 + lane]);
        #pragma unroll
        for (int w = 0; w < 4; w++)
            bkB[w] = pack2(za_l[(8 + 2 * w) * 64 + lane], za_l[(9 + 2 * w) * 64 + lane]);
        f32x16 k = feval(A1, A2, sb1, sb2, lane, q, bkA, bkB);

        // consume k1: zf = za + h6*k1; probe = za + h2*k1 (za read once)
        #pragma unroll
        for (int i = 0; i < 16; i += 2) {
            float z0v = za_l[i * 64 + lane], z1v = za_l[(i + 1) * 64 + lane];
            zf_l[i * 64 + lane]       = fmaf(h6, k[i], z0v);
            zf_l[(i + 1) * 64 + lane] = fmaf(h6, k[i + 1], z1v);
            unsigned w = pack2(fmaf(h2, k[i], z0v), fmaf(h2, k[i + 1], z1v));
            if (i < 8) bkA[i >> 1] = w; else bkB[(i - 8) >> 1] = w;
        }
        k = feval(A1, A2, sb1, sb2, lane, q, bkA, bkB);

        // consume k2: zf += h3*k2; probe = za + h2*k2
        #pragma unroll
        for (int i = 0; i < 16; i += 2) {
            float z0v = za_l[i * 64 + lane], z1v = za_l[(i + 1) * 64 + lane];
            zf_l[i * 64 + lane]       = fmaf(h3, k[i], zf_l[i * 64 + lane]);
            zf_l[(i + 1) * 64 + lane] = fmaf(h3, k[i + 1], zf_l[(i + 1) * 64 + lane]);
            unsigned w = pack2(fmaf(h2, k[i], z0v), fmaf(h2, k[i + 1], z1v));
            if (i < 8) bkA[i >> 1] = w; else bkB[(i - 8) >> 1] = w;
        }
        k = feval(A1, A2, sb1, sb2, lane, q, bkA, bkB);

        // consume k3: zf += h3*k3; probe = za + h*k3
        #pragma unroll
        for (int i = 0; i < 16; i += 2) {
            float z0v = za_l[i * 64 + lane], z1v = za_l[(i + 1) * 64 + lane];
            zf_l[i * 64 + lane]       = fmaf(h3, k[i], zf_l[i * 64 + lane]);
            zf_l[(i + 1) * 64 + lane] = fmaf(h3, k[i + 1], zf_l[(i + 1) * 64 + lane]);
            unsigned w = pack2(fmaf(h, k[i], z0v), fmaf(h, k[i + 1], z1v));
            if (i < 8) bkA[i >> 1] = w; else bkB[(i - 8) >> 1] = w;
        }
        k = feval(A1, A2, sb1, sb2, lane, q, bkA, bkB);

        // consume k4: za = zf + h6*k4
        #pragma unroll
        for (int i = 0; i < 16; i++)
            za_l[i * 64 + lane] = fmaf(h6, k[i], zf_l[i * 64 + lane]);

        // ---- trajectory[s+1]: gather from za_l (2-way banks), coalesced store ----
        float* obase = out + ((size_t)(s + 1) * BS + rowbase) * DIM;
        #pragma unroll
        for (int p = 0; p < 4; p++) {
            int d0    = (lane >> 4) + 4 * p;
            int batch = lane & 15;
            f32x4 v;
            #pragma unroll
            for (int c = 0; c < 4; c++)
                v[c] = za_l[(((d0 >> 2) * 4 + c) * 64) + (d0 & 3) * 16 + batch];
            *reinterpret_cast<f32x4*>(obase + batch * DIM + d0 * 4) = v;
        }
    }
}

extern "C" void kernel_launch(void* const* d_in, const int* in_sizes, int n_in,
                              void* d_out, int out_size, void* d_ws, size_t ws_size,
                              hipStream_t stream) {
    const float* z0 = (const float*)d_in[0];
    const float* t  = (const float*)d_in[1];
    const float* W1 = (const float*)d_in[2];
    const float* b1 = (const float*)d_in[3];
    const float* W2 = (const float*)d_in[4];
    const float* b2 = (const float*)d_in[5];
    float* out = (float*)d_out;

    node_mfma_kernel<<<dim3(NBLOCKS), dim3(BLOCK), 0, stream>>>(
        z0, t, W1, b1, W2, b2, out);
}

// Round 12
// 1014.051 us; speedup vs baseline: 19.9421x; 2.7880x over previous
//
#include <hip/hip_runtime.h>

#define DIM   64
#define HID   256
#define TLEN  21
#define BS    65536
#define BLOCK 512
#define WAVES 8
#define ROWS_PER_WAVE 16
#define ROWS_PER_BLOCK 128              // 8 waves * 16 rows
#define NBLOCKS (BS / ROWS_PER_BLOCK)   // 512

typedef __bf16    bf16x8   __attribute__((ext_vector_type(8)));
typedef float     f32x16   __attribute__((ext_vector_type(16)));
typedef float     f32x4    __attribute__((ext_vector_type(4)));
typedef unsigned  uint32x4 __attribute__((ext_vector_type(4)));

__device__ __forceinline__ bf16x8 as_bf16x8(uint32x4 u) {
    return __builtin_bit_cast(bf16x8, u);
}

__device__ __forceinline__ unsigned pack2(float a, float b) {
    __bf16 x = (__bf16)a, y = (__bf16)b;
    unsigned short ux = __builtin_bit_cast(unsigned short, x);
    unsigned short uy = __builtin_bit_cast(unsigned short, y);
    return (unsigned)ux | ((unsigned)uy << 16);
}

// tanh(x) = 1 - 2/(e^{2x}+1). Saturates correctly through exp overflow.
__device__ __forceinline__ float tanh_f(float x) {
    float e = __expf(2.0f * x);
    return 1.0f - __fdividef(2.0f, e + 1.0f);
}

// Volatile LDS fragment read: CANNOT be hoisted/CSE'd out of the feval/step
// loops. R2-R11's invariant ~8 GB HBM FETCH = LICM hoisting these
// loop-invariant ds_reads into a >256-register live set that gets homed in
// scratch (written once, reloaded every feval -> read-heavy traffic,
// insensitive to liveness restructuring and register-budget attributes).
__device__ __forceinline__ uint32x4 lds_frag_v(const volatile uint32x4* p, int i) {
    uint32x4 r = p[i];
    return r;
}
__device__ __forceinline__ f32x4 lds_bias_v(const volatile f32x4* p, int i) {
    f32x4 r = p[i];
    return r;
}

// ---------------------------------------------------------------------------
// Structure = R11 (verified absmax 0.03125): state za/zf in LDS columns
// (2-way banks), k consumed immediately after each feval, mfma_f32_16x16x32
// swapped chain, k-slot map P self-cancels, biases natural order.
// Round-12 change: ALL weight/bias LDS reads in feval are volatile.
// ---------------------------------------------------------------------------

__device__ __forceinline__ f32x16 feval(const volatile uint32x4* A1,
                                        const volatile uint32x4* A2,
                                        const volatile f32x4* b1v4,
                                        const volatile f32x4* b2v4,
                                        int lane, int q,
                                        uint32x4 bkA, uint32x4 bkB)
{
    bf16x8 b0  = as_bf16x8(bkA);
    bf16x8 b1b = as_bf16x8(bkB);

    f32x4 d20 = lds_bias_v(b2v4, 0 + q);    // sb2[q*4 + 0..3] of mt block 0
    f32x4 d21 = lds_bias_v(b2v4, 4 + q);
    f32x4 d22 = lds_bias_v(b2v4, 8 + q);
    f32x4 d23 = lds_bias_v(b2v4, 12 + q);

    #pragma unroll
    for (int kt2 = 0; kt2 < 8; kt2++) {
        f32x4 d1e = lds_bias_v(b1v4, (2 * kt2) * 4 + q);
        f32x4 d1o = lds_bias_v(b1v4, (2 * kt2 + 1) * 4 + q);

        d1e = __builtin_amdgcn_mfma_f32_16x16x32_bf16(
                  as_bf16x8(lds_frag_v(A1, (4 * kt2 + 0) * 64 + lane)), b0,  d1e, 0, 0, 0);
        d1e = __builtin_amdgcn_mfma_f32_16x16x32_bf16(
                  as_bf16x8(lds_frag_v(A1, (4 * kt2 + 1) * 64 + lane)), b1b, d1e, 0, 0, 0);
        d1o = __builtin_amdgcn_mfma_f32_16x16x32_bf16(
                  as_bf16x8(lds_frag_v(A1, (4 * kt2 + 2) * 64 + lane)), b0,  d1o, 0, 0, 0);
        d1o = __builtin_amdgcn_mfma_f32_16x16x32_bf16(
                  as_bf16x8(lds_frag_v(A1, (4 * kt2 + 3) * 64 + lane)), b1b, d1o, 0, 0, 0);

        uint32x4 bt;
        bt[0] = pack2(tanh_f(d1e[0]), tanh_f(d1e[1]));
        bt[1] = pack2(tanh_f(d1e[2]), tanh_f(d1e[3]));
        bt[2] = pack2(tanh_f(d1o[0]), tanh_f(d1o[1]));
        bt[3] = pack2(tanh_f(d1o[2]), tanh_f(d1o[3]));
        bf16x8 btb = as_bf16x8(bt);

        d20 = __builtin_amdgcn_mfma_f32_16x16x32_bf16(
                  as_bf16x8(lds_frag_v(A2, (0 * 8 + kt2) * 64 + lane)), btb, d20, 0, 0, 0);
        d21 = __builtin_amdgcn_mfma_f32_16x16x32_bf16(
                  as_bf16x8(lds_frag_v(A2, (1 * 8 + kt2) * 64 + lane)), btb, d21, 0, 0, 0);
        d22 = __builtin_amdgcn_mfma_f32_16x16x32_bf16(
                  as_bf16x8(lds_frag_v(A2, (2 * 8 + kt2) * 64 + lane)), btb, d22, 0, 0, 0);
        d23 = __builtin_amdgcn_mfma_f32_16x16x32_bf16(
                  as_bf16x8(lds_frag_v(A2, (3 * 8 + kt2) * 64 + lane)), btb, d23, 0, 0, 0);
    }

    f32x16 k;
    #pragma unroll
    for (int i = 0; i < 4; i++) {
        k[i]      = d20[i];
        k[4 + i]  = d21[i];
        k[8 + i]  = d22[i];
        k[12 + i] = d23[i];
    }
    return k;
}

extern "C" __global__ __launch_bounds__(BLOCK, 1) void node_mfma_kernel(
    const float* __restrict__ z0, const float* __restrict__ tarr,
    const float* __restrict__ W1, const float* __restrict__ b1,
    const float* __restrict__ W2, const float* __restrict__ b2,
    float* __restrict__ out)
{
    __shared__ __align__(16) unsigned short sA1[32 * 64 * 8];   // 32 KiB
    __shared__ __align__(16) unsigned short sA2[32 * 64 * 8];   // 32 KiB
    __shared__ __align__(16) float sb1[HID];                    // natural order
    __shared__ __align__(16) float sb2[DIM];
    __shared__ __align__(16) float state[WAVES][2][16 * 64];    // za, zf: 64 KiB

    const int tid  = threadIdx.x;
    const int lane = tid & 63;
    const int wv   = tid >> 6;
    const int q    = lane >> 4;

    // ---- stage W1 fragments: coalesced reads, P-permuted LDS writes ----
    for (int idx = tid; idx < DIM * HID; idx += BLOCK) {
        int hid = idx & (HID - 1);
        int dim = idx >> 8;
        int ht = hid >> 4, row = hid & 15;
        int kt = dim >> 5, dlo = dim & 31;
        int j  = (dlo & 3) | ((dlo >> 4) << 2);
        int qq = (dlo >> 2) & 3;
        __bf16 bv = (__bf16)W1[idx];
        sA1[((ht * 2 + kt) * 64 + qq * 16 + row) * 8 + j] =
            __builtin_bit_cast(unsigned short, bv);
    }
    // ---- stage W2 fragments ----
    for (int idx = tid; idx < HID * DIM; idx += BLOCK) {
        int dim = idx & (DIM - 1);
        int hid = idx >> 6;
        int mt  = dim >> 4, row = dim & 15;
        int kt2 = hid >> 5, hlo = hid & 31;
        int j   = (hlo & 3) | ((hlo >> 4) << 2);
        int qq  = (hlo >> 2) & 3;
        __bf16 bv = (__bf16)W2[idx];
        sA2[((mt * 8 + kt2) * 64 + qq * 16 + row) * 8 + j] =
            __builtin_bit_cast(unsigned short, bv);
    }
    if (tid < HID) sb1[tid] = b1[tid];
    if (tid < DIM) sb2[tid] = b2[tid];

    // ---- out[0] = z0 (coalesced block-slice copy) ----
    {
        const f32x4* src = reinterpret_cast<const f32x4*>(z0 + (size_t)blockIdx.x * ROWS_PER_BLOCK * DIM);
        f32x4*       dst = reinterpret_cast<f32x4*>(out + (size_t)blockIdx.x * ROWS_PER_BLOCK * DIM);
        for (int i = tid; i < ROWS_PER_BLOCK * DIM / 4; i += BLOCK) dst[i] = src[i];
    }

    __syncthreads();

    const int rowbase = blockIdx.x * ROWS_PER_BLOCK + wv * ROWS_PER_WAVE;
    float* za_l = state[wv][0];   // za_l[i*64 + lane]: z[batch=lane&15][dim=16*(i>>2)+4q+(i&3)]
    float* zf_l = state[wv][1];

    const volatile uint32x4* A1 = reinterpret_cast<const volatile uint32x4*>(sA1);
    const volatile uint32x4* A2 = reinterpret_cast<const volatile uint32x4*>(sA2);
    const volatile f32x4* b1v4  = reinterpret_cast<const volatile f32x4*>(sb1);
    const volatile f32x4* b2v4  = reinterpret_cast<const volatile f32x4*>(sb2);

    // ---- z0 -> za_l: coalesced dwordx4 loads, scalar LDS scatter (2-way) ----
    #pragma unroll
    for (int p = 0; p < 4; p++) {
        int d0    = (lane >> 4) + 4 * p;     // f32x4 chunk index 0..15
        int batch = lane & 15;
        f32x4 v = *reinterpret_cast<const f32x4*>(
            z0 + (size_t)(rowbase + batch) * DIM + d0 * 4);
        #pragma unroll
        for (int c = 0; c < 4; c++)
            za_l[(((d0 >> 2) * 4 + c) * 64) + (d0 & 3) * 16 + batch] = v[c];
    }

    #pragma unroll 1
    for (int s = 0; s < TLEN - 1; s++) {
        const float h  = tarr[s + 1] - tarr[s];
        const float h2 = 0.5f * h;
        const float h3 = h * (1.0f / 3.0f);
        const float h6 = h * (1.0f / 6.0f);

        // ---- k1: pack from za (LDS) ----
        uint32x4 bkA, bkB;
        #pragma unroll
        for (int w = 0; w < 4; w++)
            bkA[w] = pack2(za_l[(2 * w) * 64 + lane], za_l[(2 * w + 1) * 64 + lane]);
        #pragma unroll
        for (int w = 0; w < 4; w++)
            bkB[w] = pack2(za_l[(8 + 2 * w) * 64 + lane], za_l[(9 + 2 * w) * 64 + lane]);
        f32x16 k = feval(A1, A2, b1v4, b2v4, lane, q, bkA, bkB);

        // consume k1: zf = za + h6*k1; probe = za + h2*k1
        #pragma unroll
        for (int i = 0; i < 16; i += 2) {
            float z0v = za_l[i * 64 + lane], z1v = za_l[(i + 1) * 64 + lane];
            zf_l[i * 64 + lane]       = fmaf(h6, k[i], z0v);
            zf_l[(i + 1) * 64 + lane] = fmaf(h6, k[i + 1], z1v);
            unsigned w = pack2(fmaf(h2, k[i], z0v), fmaf(h2, k[i + 1], z1v));
            if (i < 8) bkA[i >> 1] = w; else bkB[(i - 8) >> 1] = w;
        }
        k = feval(A1, A2, b1v4, b2v4, lane, q, bkA, bkB);

        // consume k2: zf += h3*k2; probe = za + h2*k2
        #pragma unroll
        for (int i = 0; i < 16; i += 2) {
            float z0v = za_l[i * 64 + lane], z1v = za_l[(i + 1) * 64 + lane];
            zf_l[i * 64 + lane]       = fmaf(h3, k[i], zf_l[i * 64 + lane]);
            zf_l[(i + 1) * 64 + lane] = fmaf(h3, k[i + 1], zf_l[(i + 1) * 64 + lane]);
            unsigned w = pack2(fmaf(h2, k[i], z0v), fmaf(h2, k[i + 1], z1v));
            if (i < 8) bkA[i >> 1] = w; else bkB[(i - 8) >> 1] = w;
        }
        k = feval(A1, A2, b1v4, b2v4, lane, q, bkA, bkB);

        // consume k3: zf += h3*k3; probe = za + h*k3
        #pragma unroll
        for (int i = 0; i < 16; i += 2) {
            float z0v = za_l[i * 64 + lane], z1v = za_l[(i + 1) * 64 + lane];
            zf_l[i * 64 + lane]       = fmaf(h3, k[i], zf_l[i * 64 + lane]);
            zf_l[(i + 1) * 64 + lane] = fmaf(h3, k[i + 1], zf_l[(i + 1) * 64 + lane]);
            unsigned w = pack2(fmaf(h, k[i], z0v), fmaf(h, k[i + 1], z1v));
            if (i < 8) bkA[i >> 1] = w; else bkB[(i - 8) >> 1] = w;
        }
        k = feval(A1, A2, b1v4, b2v4, lane, q, bkA, bkB);

        // consume k4: za = zf + h6*k4
        #pragma unroll
        for (int i = 0; i < 16; i++)
            za_l[i * 64 + lane] = fmaf(h6, k[i], zf_l[i * 64 + lane]);

        // ---- trajectory[s+1]: gather from za_l (2-way banks), coalesced store ----
        float* obase = out + ((size_t)(s + 1) * BS + rowbase) * DIM;
        #pragma unroll
        for (int p = 0; p < 4; p++) {
            int d0    = (lane >> 4) + 4 * p;
            int batch = lane & 15;
            f32x4 v;
            #pragma unroll
            for (int c = 0; c < 4; c++)
                v[c] = za_l[(((d0 >> 2) * 4 + c) * 64) + (d0 & 3) * 16 + batch];
            *reinterpret_cast<f32x4*>(obase + batch * DIM + d0 * 4) = v;
        }
    }
}

extern "C" void kernel_launch(void* const* d_in, const int* in_sizes, int n_in,
                              void* d_out, int out_size, void* d_ws, size_t ws_size,
                              hipStream_t stream) {
    const float* z0 = (const float*)d_in[0];
    const float* t  = (const float*)d_in[1];
    const float* W1 = (const float*)d_in[2];
    const float* b1 = (const float*)d_in[3];
    const float* W2 = (const float*)d_in[4];
    const float* b2 = (const float*)d_in[5];
    float* out = (float*)d_out;

    node_mfma_kernel<<<dim3(NBLOCKS), dim3(BLOCK), 0, stream>>>(
        z0, t, W1, b1, W2, b2, out);
}